// Round 4
// baseline (497.370 us; speedup 1.0000x reference)
//
#include <hip/hip_runtime.h>
#include <hip/hip_cooperative_groups.h>
#include <stdint.h>

namespace cg = cooperative_groups;

#define B_N 1024
#define K_N 64
#define O_N 4096
#define I_N 4096
#define H16S 260

typedef float nvec4 __attribute__((ext_vector_type(4)));

// Per-group topk shared-memory overlay (18,704 B; x4 groups = 74.8 KB).
struct TopkSh {
  unsigned int hist[256];
  unsigned int hist16[16 * H16S];
  unsigned int sel_u[64];
  int sel_i[64];
  int eqlist[128];
  unsigned int s_cntgt, s_cnteq, s_remaining, s_prefix;
};

// ---------------------------------------------------------------------------
// Bit-exact gemv inner pass (identical arithmetic chain to the R11/R13
// winner): per (b,o) ascending-k, unfused mul/add, bias last.
// ---------------------------------------------------------------------------
#define GEMV_COMPUTE(G)                                                   \
  do {                                                                    \
    const int o0 = (G)*8;                                                 \
    const int b = t;                                                      \
    const float4 bvA = *(const float4*)(bias + o0);                       \
    const float4 bvB = *(const float4*)(bias + o0 + 4);                   \
    float4 aA = make_float4(0.f, 0.f, 0.f, 0.f);                          \
    float4 aB = make_float4(0.f, 0.f, 0.f, 0.f);                          \
    float xr[4];                                                          \
    int ir[4];                                                            \
    _Pragma("unroll") for (int d = 0; d < 4; ++d) {                       \
      xr[d] = xT[d * B_N + b];                                            \
      ir[d] = idxT[d * B_N + b];                                          \
    }                                                                     \
    _Pragma("unroll") for (int k = 0; k < K_N; ++k) {                     \
      const float xk = xr[k & 3];                                         \
      const int i = ir[k & 3];                                            \
      if (k + 4 < K_N) {                                                  \
        xr[k & 3] = xT[(k + 4) * B_N + b];                                \
        ir[k & 3] = idxT[(k + 4) * B_N + b];                              \
      }                                                                   \
      const float4 wA = Wi[i];                                            \
      const float4 wB = Wi[I_N + i];                                      \
      aA.x = __fadd_rn(aA.x, __fmul_rn(xk, wA.x));                        \
      aA.y = __fadd_rn(aA.y, __fmul_rn(xk, wA.y));                        \
      aA.z = __fadd_rn(aA.z, __fmul_rn(xk, wA.z));                        \
      aA.w = __fadd_rn(aA.w, __fmul_rn(xk, wA.w));                        \
      aB.x = __fadd_rn(aB.x, __fmul_rn(xk, wB.x));                        \
      aB.y = __fadd_rn(aB.y, __fmul_rn(xk, wB.y));                        \
      aB.z = __fadd_rn(aB.z, __fmul_rn(xk, wB.z));                        \
      aB.w = __fadd_rn(aB.w, __fmul_rn(xk, wB.w));                        \
    }                                                                     \
    aA.x = __fadd_rn(aA.x, bvA.x);                                        \
    aA.y = __fadd_rn(aA.y, bvA.y);                                        \
    aA.z = __fadd_rn(aA.z, bvA.z);                                        \
    aA.w = __fadd_rn(aA.w, bvA.w);                                        \
    aB.x = __fadd_rn(aB.x, bvB.x);                                        \
    aB.y = __fadd_rn(aB.y, bvB.y);                                        \
    aB.z = __fadd_rn(aB.z, bvB.z);                                        \
    aB.w = __fadd_rn(aB.w, bvB.w);                                        \
    *(float4*)(res + (size_t)b * O_N + o0) = aA;                          \
    *(float4*)(res + (size_t)b * O_N + o0 + 4) = aB;                      \
  } while (0)

// ---------------------------------------------------------------------------
// R14: single cooperative kernel. 256 blocks x 1024 threads x 128 KB LDS
// (exactly 1 block/CU x 256 CUs => co-resident).
// Phase A: W tile-0 reg-prefetch (all blocks) + x/idx transpose (blocks 0-7,
//          hidden under the other blocks' prefetch wait). grid.sync.
// Phase B: gemv, byte-identical arithmetic to R13's 45.0us winner.
// Phase C: topk, 4 rows/block as 4x256-thread groups; block-wide barriers
//          are safe because control flow at every __syncthreads is uniform
//          across groups (fixed 4-round radix loop).
// Rationale: total-minus-gemv has been stable at ~100-107us across R0-R13
// while topk < 44.5us and xpose ~3us => >=55us launch/gap overhead. This
// removes 2 of 3 launches and hides xpose.
// ---------------------------------------------------------------------------
__global__ __launch_bounds__(1024, 1) void fused_all(
    const float* __restrict__ W, const float* __restrict__ x,
    const float* __restrict__ idxf, const float* __restrict__ bias,
    float* __restrict__ xT, float* __restrict__ idxTf,
    float* __restrict__ res, float* __restrict__ out) {
  __shared__ __align__(16) float4 Wi[2 * I_N];  // 128 KB, overlaid per phase
  cg::grid_group grid = cg::this_grid();

  const int t = threadIdx.x;
  const int bx = blockIdx.x;
  const int xcd = bx & 7;
  const int jjb = bx >> 3;             // 0..31
  const int g0 = (xcd * 32 + jjb) * 2; // even 8-row group in [0,512)
  const int i0 = 4 * t;

  // ---- W tile-0 prefetch into registers (all blocks) ----
  nvec4 r0, r1, r2, r3, r4, r5, r6, r7;
  {
    const float* Wp = W + (size_t)g0 * 8 * I_N + i0;
    r0 = __builtin_nontemporal_load((const nvec4*)(Wp + 0 * (size_t)I_N));
    r1 = __builtin_nontemporal_load((const nvec4*)(Wp + 1 * (size_t)I_N));
    r2 = __builtin_nontemporal_load((const nvec4*)(Wp + 2 * (size_t)I_N));
    r3 = __builtin_nontemporal_load((const nvec4*)(Wp + 3 * (size_t)I_N));
    r4 = __builtin_nontemporal_load((const nvec4*)(Wp + 4 * (size_t)I_N));
    r5 = __builtin_nontemporal_load((const nvec4*)(Wp + 5 * (size_t)I_N));
    r6 = __builtin_nontemporal_load((const nvec4*)(Wp + 6 * (size_t)I_N));
    r7 = __builtin_nontemporal_load((const nvec4*)(Wp + 7 * (size_t)I_N));
  }

  // ---- Phase A: transpose x and idx (blocks 0-7; 4 tile-jobs each) ----
  if (bx < 8) {
    float* tile = (float*)Wi;  // 64 x 65 float overlay (16.6 KB)
    for (int job = bx * 4; job < bx * 4 + 4; ++job) {
      const int which = job >> 4;
      const int b0 = (job & 15) * 64;
      const float* src = which ? idxf : x;
      float* dst = which ? idxTf : xT;
      {
        const int r = t & 63;
        const int q = t >> 6;  // 0..15
        const float4 v =
            *(const float4*)(src + (size_t)(b0 + r) * K_N + 4 * q);
        tile[r * 65 + 4 * q + 0] = v.x;
        tile[r * 65 + 4 * q + 1] = v.y;
        tile[r * 65 + 4 * q + 2] = v.z;
        tile[r * 65 + 4 * q + 3] = v.w;
      }
      __syncthreads();
      {
        const int kk = t & 63;
        const int qb = t >> 6;  // 0..15
        float4 v;
        v.x = tile[(4 * qb + 0) * 65 + kk];
        v.y = tile[(4 * qb + 1) * 65 + kk];
        v.z = tile[(4 * qb + 2) * 65 + kk];
        v.w = tile[(4 * qb + 3) * 65 + kk];
        *(float4*)(dst + (size_t)kk * B_N + b0 + 4 * qb) = v;
      }
      __syncthreads();
    }
  }

  grid.sync();

  // ---- Phase B: gemv (R13 winner structure) ----
  const int* idxT = (const int*)idxTf;
  // stage pass 0 from prefetched regs
  Wi[i0 + 0] = make_float4(r0.x, r1.x, r2.x, r3.x);
  Wi[i0 + 1] = make_float4(r0.y, r1.y, r2.y, r3.y);
  Wi[i0 + 2] = make_float4(r0.z, r1.z, r2.z, r3.z);
  Wi[i0 + 3] = make_float4(r0.w, r1.w, r2.w, r3.w);
  Wi[I_N + i0 + 0] = make_float4(r4.x, r5.x, r6.x, r7.x);
  Wi[I_N + i0 + 1] = make_float4(r4.y, r5.y, r6.y, r7.y);
  Wi[I_N + i0 + 2] = make_float4(r4.z, r5.z, r6.z, r7.z);
  Wi[I_N + i0 + 3] = make_float4(r4.w, r5.w, r6.w, r7.w);
  // prefetch pass-1 tile (hides under pass-0 k-loop)
  {
    const float* Wp = W + ((size_t)g0 + 1) * 8 * I_N + i0;
    r0 = __builtin_nontemporal_load((const nvec4*)(Wp + 0 * (size_t)I_N));
    r1 = __builtin_nontemporal_load((const nvec4*)(Wp + 1 * (size_t)I_N));
    r2 = __builtin_nontemporal_load((const nvec4*)(Wp + 2 * (size_t)I_N));
    r3 = __builtin_nontemporal_load((const nvec4*)(Wp + 3 * (size_t)I_N));
    r4 = __builtin_nontemporal_load((const nvec4*)(Wp + 4 * (size_t)I_N));
    r5 = __builtin_nontemporal_load((const nvec4*)(Wp + 5 * (size_t)I_N));
    r6 = __builtin_nontemporal_load((const nvec4*)(Wp + 6 * (size_t)I_N));
    r7 = __builtin_nontemporal_load((const nvec4*)(Wp + 7 * (size_t)I_N));
  }
  __syncthreads();

  GEMV_COMPUTE(g0);

  __syncthreads();  // all pass-0 reads done before overwriting the tile
  Wi[i0 + 0] = make_float4(r0.x, r1.x, r2.x, r3.x);
  Wi[i0 + 1] = make_float4(r0.y, r1.y, r2.y, r3.y);
  Wi[i0 + 2] = make_float4(r0.z, r1.z, r2.z, r3.z);
  Wi[i0 + 3] = make_float4(r0.w, r1.w, r2.w, r3.w);
  Wi[I_N + i0 + 0] = make_float4(r4.x, r5.x, r6.x, r7.x);
  Wi[I_N + i0 + 1] = make_float4(r4.y, r5.y, r6.y, r7.y);
  Wi[I_N + i0 + 2] = make_float4(r4.z, r5.z, r6.z, r7.z);
  Wi[I_N + i0 + 3] = make_float4(r4.w, r5.w, r6.w, r7.w);
  __syncthreads();

  GEMV_COMPUTE(g0 + 1);

  grid.sync();

  // ---- Phase C: topk, 4 rows per block (4 x 256-thread groups) ----
  {
    const int g = t >> 8;    // group 0..3
    const int tl = t & 255;  // lane within group
    const int row = bx * 4 + g;
    TopkSh* sh = ((TopkSh*)Wi) + g;

    sh->hist[tl] = 0u;
#pragma unroll
    for (int j = 0; j < 17; ++j) {
      const int z = tl + 256 * j;
      if (z < 16 * H16S) sh->hist16[z] = 0u;
    }
    if (tl == 0) {
      sh->s_remaining = 64u;
      sh->s_prefix = 0u;
      sh->s_cntgt = 0u;
      sh->s_cnteq = 0u;
    }

    unsigned int myu[16];
#pragma unroll
    for (int jf = 0; jf < 4; ++jf) {
      const float4 v =
          *(const float4*)(res + (size_t)row * O_N + 1024 * jf + 4 * tl);
      const float fv[4] = {v.x, v.y, v.z, v.w};
#pragma unroll
      for (int c = 0; c < 4; ++c) {
        const unsigned int s = __float_as_uint(fv[c]);
        myu[jf * 4 + c] = (s & 0x80000000u) ? ~s : (s | 0x80000000u);
      }
    }
    __syncthreads();

    for (int round = 3; round >= 0; --round) {
      const int shift = round * 8;
      const unsigned int pfx = sh->s_prefix;
      const unsigned int rem = sh->s_remaining;
      if (round == 3) {
        const int rep = (tl & 15) * H16S;
#pragma unroll
        for (int j = 0; j < 16; ++j)
          atomicAdd(&sh->hist16[rep + (myu[j] >> 24)], 1u);
      } else {
        const unsigned int himask = 0xFFFFFFFFu << (shift + 8);
#pragma unroll
        for (int j = 0; j < 16; ++j) {
          if ((myu[j] & himask) == (pfx & himask))
            atomicAdd(&sh->hist[(myu[j] >> shift) & 255u], 1u);
        }
      }
      __syncthreads();
      if (tl < 64) {
        uint4 h;
        if (round == 3) {
          h = make_uint4(0u, 0u, 0u, 0u);
#pragma unroll
          for (int r = 0; r < 16; ++r) {
            const uint4 hh = *(const uint4*)&sh->hist16[r * H16S + 4 * tl];
            h.x += hh.x;
            h.y += hh.y;
            h.z += hh.z;
            h.w += hh.w;
          }
        } else {
          h = *(const uint4*)&sh->hist[4 * tl];
        }
        unsigned int s0 = h.x + h.y + h.z + h.w;
        unsigned int run = s0;
#pragma unroll
        for (int off = 1; off < 64; off <<= 1) {
          const unsigned int v = __shfl_down(run, off, 64);
          if (tl + off < 64) run += v;
        }
        const unsigned int above = run - s0;
        unsigned int cge[4], cgt[4];
        cgt[3] = above;
        cge[3] = above + h.w;
        cgt[2] = cge[3];
        cge[2] = cge[3] + h.z;
        cgt[1] = cge[2];
        cge[1] = cge[2] + h.y;
        cgt[0] = cge[1];
        cge[0] = cge[1] + h.x;
#pragma unroll
        for (int j = 0; j < 4; ++j) {
          if (cge[j] >= rem && cgt[j] < rem) {
            sh->s_prefix = pfx | ((unsigned int)(4 * tl + j) << shift);
            sh->s_remaining = rem - cgt[j];
          }
        }
        *(uint4*)&sh->hist[4 * tl] = make_uint4(0u, 0u, 0u, 0u);
      }
      __syncthreads();
    }
    const unsigned int ustar = sh->s_prefix;

#pragma unroll
    for (int j = 0; j < 16; ++j) {
      const unsigned int u = myu[j];
      const int oi = 4 * tl + (j & 3) + 1024 * (j >> 2);
      if (u > ustar) {
        unsigned int p = atomicAdd(&sh->s_cntgt, 1u);
        sh->sel_u[p] = u;
        sh->sel_i[p] = oi;
      } else if (u == ustar) {
        unsigned int p = atomicAdd(&sh->s_cnteq, 1u);
        if (p < 128u) sh->eqlist[p] = oi;
      }
    }
    __syncthreads();

    if (tl == 0 && sh->s_cnteq > 1u) {
      int n = (int)(sh->s_cnteq < 128u ? sh->s_cnteq : 128u);
      for (int a = 1; a < n; ++a) {
        int v = sh->eqlist[a];
        int c = a;
        while (c > 0 && sh->eqlist[c - 1] > v) {
          sh->eqlist[c] = sh->eqlist[c - 1];
          --c;
        }
        sh->eqlist[c] = v;
      }
    }
    __syncthreads();

    if (tl < 64) {
      const int n_gt = (int)sh->s_cntgt;
      unsigned int u;
      int oi;
      if (tl < n_gt) {
        u = sh->sel_u[tl];
        oi = sh->sel_i[tl];
      } else {
        u = ustar;
        oi = sh->eqlist[tl - n_gt];
      }
      unsigned long long key =
          ((unsigned long long)(~u) << 32) | (unsigned int)oi;
      for (int kk = 2; kk <= 64; kk <<= 1) {
        for (int jj = kk >> 1; jj > 0; jj >>= 1) {
          unsigned long long partner = __shfl_xor(key, jj, 64);
          const bool up = ((tl & kk) == 0);
          const bool lower = ((tl & jj) == 0);
          unsigned long long mn = key < partner ? key : partner;
          unsigned long long mx = key < partner ? partner : key;
          key = (up == lower) ? mn : mx;
        }
      }
      const unsigned int su = ~(unsigned int)(key >> 32);
      const int so = (int)(key & 0xFFFFFFFFu);
      const float f = (su & 0x80000000u) ? __uint_as_float(su ^ 0x80000000u)
                                         : __uint_as_float(~su);
      out[row * 64 + tl] = f;
      out[B_N * 64 + row * 64 + tl] = (float)so;
    }
  }
}

// ===========================================================================
// Fallback path (R13 3-kernel pipeline) — used if cooperative launch fails.
// ===========================================================================
__global__ __launch_bounds__(256) void xpose_small(
    const float* __restrict__ x, const float* __restrict__ idxf,
    float* __restrict__ xT, float* __restrict__ idxTf) {
  __shared__ float tile[64][65];
  const int t = threadIdx.x;
  const int which = blockIdx.x >> 4;
  const int b0 = (blockIdx.x & 15) * 64;
  const float* src = which ? idxf : x;
  float* dst = which ? idxTf : xT;
  {
    const int r = t & 63;
    const int q0 = t >> 6;
#pragma unroll
    for (int jj = 0; jj < 4; ++jj) {
      const int q = q0 + 4 * jj;
      const float4 v = *(const float4*)(src + (size_t)(b0 + r) * K_N + 4 * q);
      tile[r][4 * q + 0] = v.x;
      tile[r][4 * q + 1] = v.y;
      tile[r][4 * q + 2] = v.z;
      tile[r][4 * q + 3] = v.w;
    }
  }
  __syncthreads();
  {
    const int kk = t & 63;
    const int q0 = t >> 6;
#pragma unroll
    for (int jj = 0; jj < 4; ++jj) {
      const int qb = q0 + 4 * jj;
      float4 v;
      v.x = tile[4 * qb + 0][kk];
      v.y = tile[4 * qb + 1][kk];
      v.z = tile[4 * qb + 2][kk];
      v.w = tile[4 * qb + 3][kk];
      *(float4*)(dst + (size_t)kk * B_N + b0 + 4 * qb) = v;
    }
  }
}

__global__ __launch_bounds__(1024, 4) void gemv_lds8(
    const float* __restrict__ W, const float* __restrict__ xT,
    const int* __restrict__ idxT, const float* __restrict__ bias,
    float* __restrict__ res) {
  __shared__ float4 Wi[2 * I_N];  // 128 KB
  const int t = threadIdx.x;
  const int i0 = 4 * t;
  const int xcd = blockIdx.x & 7;
  const int jj = blockIdx.x >> 3;
  const int g0 = (xcd * 32 + jj) * 2;

  nvec4 r0, r1, r2, r3, r4, r5, r6, r7;
  {
    const float* Wp = W + (size_t)g0 * 8 * I_N + i0;
    r0 = __builtin_nontemporal_load((const nvec4*)(Wp + 0 * (size_t)I_N));
    r1 = __builtin_nontemporal_load((const nvec4*)(Wp + 1 * (size_t)I_N));
    r2 = __builtin_nontemporal_load((const nvec4*)(Wp + 2 * (size_t)I_N));
    r3 = __builtin_nontemporal_load((const nvec4*)(Wp + 3 * (size_t)I_N));
    r4 = __builtin_nontemporal_load((const nvec4*)(Wp + 4 * (size_t)I_N));
    r5 = __builtin_nontemporal_load((const nvec4*)(Wp + 5 * (size_t)I_N));
    r6 = __builtin_nontemporal_load((const nvec4*)(Wp + 6 * (size_t)I_N));
    r7 = __builtin_nontemporal_load((const nvec4*)(Wp + 7 * (size_t)I_N));
  }
  Wi[i0 + 0] = make_float4(r0.x, r1.x, r2.x, r3.x);
  Wi[i0 + 1] = make_float4(r0.y, r1.y, r2.y, r3.y);
  Wi[i0 + 2] = make_float4(r0.z, r1.z, r2.z, r3.z);
  Wi[i0 + 3] = make_float4(r0.w, r1.w, r2.w, r3.w);
  Wi[I_N + i0 + 0] = make_float4(r4.x, r5.x, r6.x, r7.x);
  Wi[I_N + i0 + 1] = make_float4(r4.y, r5.y, r6.y, r7.y);
  Wi[I_N + i0 + 2] = make_float4(r4.z, r5.z, r6.z, r7.z);
  Wi[I_N + i0 + 3] = make_float4(r4.w, r5.w, r6.w, r7.w);
  {
    const float* Wp = W + ((size_t)g0 + 1) * 8 * I_N + i0;
    r0 = __builtin_nontemporal_load((const nvec4*)(Wp + 0 * (size_t)I_N));
    r1 = __builtin_nontemporal_load((const nvec4*)(Wp + 1 * (size_t)I_N));
    r2 = __builtin_nontemporal_load((const nvec4*)(Wp + 2 * (size_t)I_N));
    r3 = __builtin_nontemporal_load((const nvec4*)(Wp + 3 * (size_t)I_N));
    r4 = __builtin_nontemporal_load((const nvec4*)(Wp + 4 * (size_t)I_N));
    r5 = __builtin_nontemporal_load((const nvec4*)(Wp + 5 * (size_t)I_N));
    r6 = __builtin_nontemporal_load((const nvec4*)(Wp + 6 * (size_t)I_N));
    r7 = __builtin_nontemporal_load((const nvec4*)(Wp + 7 * (size_t)I_N));
  }
  __syncthreads();

  GEMV_COMPUTE(g0);

  __syncthreads();
  Wi[i0 + 0] = make_float4(r0.x, r1.x, r2.x, r3.x);
  Wi[i0 + 1] = make_float4(r0.y, r1.y, r2.y, r3.y);
  Wi[i0 + 2] = make_float4(r0.z, r1.z, r2.z, r3.z);
  Wi[i0 + 3] = make_float4(r0.w, r1.w, r2.w, r3.w);
  Wi[I_N + i0 + 0] = make_float4(r4.x, r5.x, r6.x, r7.x);
  Wi[I_N + i0 + 1] = make_float4(r4.y, r5.y, r6.y, r7.y);
  Wi[I_N + i0 + 2] = make_float4(r4.z, r5.z, r6.z, r7.z);
  Wi[I_N + i0 + 3] = make_float4(r4.w, r5.w, r6.w, r7.w);
  __syncthreads();

  GEMV_COMPUTE(g0 + 1);
}

__global__ __launch_bounds__(256) void topk_phase(
    const float* __restrict__ res, float* __restrict__ out) {
  __shared__ __align__(16) unsigned int hist[256];
  __shared__ __align__(16) unsigned int hist16[16 * H16S];
  __shared__ unsigned int sel_u[64];
  __shared__ int sel_i[64];
  __shared__ int eqlist[128];
  __shared__ unsigned int s_cntgt, s_cnteq;
  __shared__ unsigned int s_remaining, s_prefix;

  const int t = threadIdx.x;
  const int b = blockIdx.x;

  hist[t] = 0u;
#pragma unroll
  for (int j = 0; j < 17; ++j) {
    const int z = t + 256 * j;
    if (z < 16 * H16S) hist16[z] = 0u;
  }
  if (t == 0) {
    s_remaining = 64u;
    s_prefix = 0u;
    s_cntgt = 0u;
    s_cnteq = 0u;
  }

  unsigned int myu[16];
#pragma unroll
  for (int jf = 0; jf < 4; ++jf) {
    const float4 v =
        *(const float4*)(res + (size_t)b * O_N + 1024 * jf + 4 * t);
    const float fv[4] = {v.x, v.y, v.z, v.w};
#pragma unroll
    for (int c = 0; c < 4; ++c) {
      const unsigned int s = __float_as_uint(fv[c]);
      myu[jf * 4 + c] = (s & 0x80000000u) ? ~s : (s | 0x80000000u);
    }
  }
  __syncthreads();

  for (int round = 3; round >= 0; --round) {
    const int shift = round * 8;
    const unsigned int pfx = s_prefix;
    const unsigned int rem = s_remaining;
    if (round == 3) {
      const int rep = (t & 15) * H16S;
#pragma unroll
      for (int j = 0; j < 16; ++j)
        atomicAdd(&hist16[rep + (myu[j] >> 24)], 1u);
    } else {
      const unsigned int himask = 0xFFFFFFFFu << (shift + 8);
#pragma unroll
      for (int j = 0; j < 16; ++j) {
        if ((myu[j] & himask) == (pfx & himask))
          atomicAdd(&hist[(myu[j] >> shift) & 255u], 1u);
      }
    }
    __syncthreads();
    if (t < 64) {
      uint4 h;
      if (round == 3) {
        h = make_uint4(0u, 0u, 0u, 0u);
#pragma unroll
        for (int r = 0; r < 16; ++r) {
          const uint4 hh = *(const uint4*)&hist16[r * H16S + 4 * t];
          h.x += hh.x;
          h.y += hh.y;
          h.z += hh.z;
          h.w += hh.w;
        }
      } else {
        h = *(const uint4*)&hist[4 * t];
      }
      unsigned int s0 = h.x + h.y + h.z + h.w;
      unsigned int run = s0;
#pragma unroll
      for (int off = 1; off < 64; off <<= 1) {
        const unsigned int v = __shfl_down(run, off, 64);
        if (t + off < 64) run += v;
      }
      const unsigned int above = run - s0;
      unsigned int cge[4], cgt[4];
      cgt[3] = above;
      cge[3] = above + h.w;
      cgt[2] = cge[3];
      cge[2] = cge[3] + h.z;
      cgt[1] = cge[2];
      cge[1] = cge[2] + h.y;
      cgt[0] = cge[1];
      cge[0] = cge[1] + h.x;
#pragma unroll
      for (int j = 0; j < 4; ++j) {
        if (cge[j] >= rem && cgt[j] < rem) {
          s_prefix = pfx | ((unsigned int)(4 * t + j) << shift);
          s_remaining = rem - cgt[j];
        }
      }
      *(uint4*)&hist[4 * t] = make_uint4(0u, 0u, 0u, 0u);
    }
    __syncthreads();
  }
  const unsigned int ustar = s_prefix;

#pragma unroll
  for (int j = 0; j < 16; ++j) {
    const unsigned int u = myu[j];
    const int oi = 4 * t + (j & 3) + 1024 * (j >> 2);
    if (u > ustar) {
      unsigned int p = atomicAdd(&s_cntgt, 1u);
      sel_u[p] = u;
      sel_i[p] = oi;
    } else if (u == ustar) {
      unsigned int p = atomicAdd(&s_cnteq, 1u);
      if (p < 128u) eqlist[p] = oi;
    }
  }
  __syncthreads();

  if (t == 0 && s_cnteq > 1u) {
    int n = (int)(s_cnteq < 128u ? s_cnteq : 128u);
    for (int a = 1; a < n; ++a) {
      int v = eqlist[a];
      int c = a;
      while (c > 0 && eqlist[c - 1] > v) {
        eqlist[c] = eqlist[c - 1];
        --c;
      }
      eqlist[c] = v;
    }
  }
  __syncthreads();

  if (t < 64) {
    const int n_gt = (int)s_cntgt;
    unsigned int u;
    int oi;
    if (t < n_gt) {
      u = sel_u[t];
      oi = sel_i[t];
    } else {
      u = ustar;
      oi = eqlist[t - n_gt];
    }
    unsigned long long key =
        ((unsigned long long)(~u) << 32) | (unsigned int)oi;
    for (int kk = 2; kk <= 64; kk <<= 1) {
      for (int jj = kk >> 1; jj > 0; jj >>= 1) {
        unsigned long long partner = __shfl_xor(key, jj, 64);
        const bool up = ((t & kk) == 0);
        const bool lower = ((t & jj) == 0);
        unsigned long long mn = key < partner ? key : partner;
        unsigned long long mx = key < partner ? partner : key;
        key = (up == lower) ? mn : mx;
      }
    }
    const unsigned int su = ~(unsigned int)(key >> 32);
    const int so = (int)(key & 0xFFFFFFFFu);
    const float f = (su & 0x80000000u) ? __uint_as_float(su ^ 0x80000000u)
                                       : __uint_as_float(~su);
    out[b * 64 + t] = f;
    out[B_N * 64 + b * 64 + t] = (float)so;
  }
}

// ---------------------------------------------------------------------------
// Fallback: fused single-kernel path on raw W (used only if ws is too small).
// ---------------------------------------------------------------------------
__global__ __launch_bounds__(256) void selgemv_topk(
    const float* __restrict__ x, const float* __restrict__ Wsrc,
    const float* __restrict__ bias, const int* __restrict__ idx,
    float* __restrict__ out) {
  __shared__ float sx[K_N];
  __shared__ int si[K_N];
  __shared__ float svals[O_N];
  __shared__ unsigned int hist[256];
  __shared__ unsigned int scan[256];
  __shared__ unsigned int sel_u[64];
  __shared__ int sel_i[64];
  __shared__ int eqlist[128];
  __shared__ unsigned int s_T, s_ngt, s_cntgt, s_cnteq;
  __shared__ unsigned int s_remaining, s_prefix;

  const int t = threadIdx.x;
  const int b = blockIdx.x;

  if (t < K_N) {
    sx[t] = x[b * K_N + t];
    si[t] = idx[b * K_N + t];
  }
  if (t == 0) {
    s_remaining = 64u;
    s_prefix = 0u;
    s_cntgt = 0u;
    s_cnteq = 0u;
  }
  __syncthreads();

  float acc[16];
#pragma unroll
  for (int j = 0; j < 16; ++j) acc[j] = 0.0f;

  for (int k = 0; k < K_N; ++k) {
    const float xk = sx[k];
    const int ik = si[k];
#pragma unroll
    for (int j = 0; j < 4; ++j) {
      int o0 = (j * 256 + t) * 4;
#pragma unroll
      for (int c = 0; c < 4; ++c) {
        float w = Wsrc[(size_t)(o0 + c) * I_N + ik];
        acc[4 * j + c] = __fadd_rn(acc[4 * j + c], __fmul_rn(xk, w));
      }
    }
  }

#pragma unroll
  for (int j = 0; j < 4; ++j) {
    int g = j * 256 + t;
    float4 bb = ((const float4*)bias)[g];
    float4 r;
    r.x = __fadd_rn(acc[4 * j + 0], bb.x);
    r.y = __fadd_rn(acc[4 * j + 1], bb.y);
    r.z = __fadd_rn(acc[4 * j + 2], bb.z);
    r.w = __fadd_rn(acc[4 * j + 3], bb.w);
    ((float4*)svals)[g] = r;
  }
  __syncthreads();

  unsigned int myu[16];
#pragma unroll
  for (int j = 0; j < 16; ++j) {
    float f = svals[t + 256 * j];
    unsigned int s = __float_as_uint(f);
    myu[j] = (s & 0x80000000u) ? ~s : (s | 0x80000000u);
  }

  for (int round = 3; round >= 0; --round) {
    const int shift = round * 8;
    hist[t] = 0u;
    __syncthreads();
    const unsigned int pfx = s_prefix;
    const unsigned int rem = s_remaining;
    const unsigned int himask =
        (round == 3) ? 0u : (0xFFFFFFFFu << (shift + 8));
#pragma unroll
    for (int j = 0; j < 16; ++j) {
      if ((myu[j] & himask) == (pfx & himask))
        atomicAdd(&hist[(myu[j] >> shift) & 255u], 1u);
    }
    __syncthreads();
    scan[t] = hist[t];
    __syncthreads();
    for (int off = 1; off < 256; off <<= 1) {
      unsigned int v = (t + off < 256) ? scan[t + off] : 0u;
      __syncthreads();
      scan[t] += v;
      __syncthreads();
    }
    const unsigned int c_ge = scan[t];
    const unsigned int c_gt = (t < 255) ? scan[t + 1] : 0u;
    if (c_ge >= rem && c_gt < rem) {
      s_T = (unsigned int)t;
      s_ngt = c_gt;
    }
    __syncthreads();
    if (t == 0) {
      s_prefix |= (s_T << shift);
      s_remaining -= s_ngt;
    }
    __syncthreads();
  }
  const unsigned int ustar = s_prefix;

#pragma unroll
  for (int j = 0; j < 16; ++j) {
    const unsigned int u = myu[j];
    if (u > ustar) {
      unsigned int p = atomicAdd(&s_cntgt, 1u);
      sel_u[p] = u;
      sel_i[p] = t + 256 * j;
    } else if (u == ustar) {
      unsigned int p = atomicAdd(&s_cnteq, 1u);
      if (p < 128u) eqlist[p] = t + 256 * j;
    }
  }
  __syncthreads();

  if (t == 0 && s_cnteq > 1u) {
    int n = (int)(s_cnteq < 128u ? s_cnteq : 128u);
    for (int a = 1; a < n; ++a) {
      int v = eqlist[a];
      int c = a;
      while (c > 0 && eqlist[c - 1] > v) {
        eqlist[c] = eqlist[c - 1];
        --c;
      }
      eqlist[c] = v;
    }
  }
  __syncthreads();

  if (t < 64) {
    const int n_gt = (int)s_cntgt;
    unsigned int u;
    int oi;
    if (t < n_gt) {
      u = sel_u[t];
      oi = sel_i[t];
    } else {
      u = ustar;
      oi = eqlist[t - n_gt];
    }
    unsigned long long key =
        ((unsigned long long)(~u) << 32) | (unsigned int)oi;
    for (int kk = 2; kk <= 64; kk <<= 1) {
      for (int jj = kk >> 1; jj > 0; jj >>= 1) {
        unsigned long long partner = __shfl_xor(key, jj, 64);
        const bool up = ((t & kk) == 0);
        const bool lower = ((t & jj) == 0);
        unsigned long long mn = key < partner ? key : partner;
        unsigned long long mx = key < partner ? partner : key;
        key = (up == lower) ? mn : mx;
      }
    }
    const unsigned int su = ~(unsigned int)(key >> 32);
    const int so = (int)(key & 0xFFFFFFFFu);
    const float f = (su & 0x80000000u) ? __uint_as_float(su ^ 0x80000000u)
                                       : __uint_as_float(~su);
    out[b * 64 + t] = f;
    out[B_N * 64 + b * 64 + t] = (float)so;
  }
}

extern "C" void kernel_launch(void* const* d_in, const int* in_sizes, int n_in,
                              void* d_out, int out_size, void* d_ws,
                              size_t ws_size, hipStream_t stream) {
  const float* x = (const float*)d_in[0];     // (1024, 64)
  const float* W = (const float*)d_in[1];     // (4096, 4096)
  const float* bias = (const float*)d_in[2];  // (4096,)
  const int* idx = (const int*)d_in[3];       // (1024, 64) int32
  float* out = (float*)d_out;

  const size_t xT_bytes = (size_t)K_N * B_N * sizeof(float);   // 256 KB
  const size_t idxT_bytes = xT_bytes;                          // 256 KB
  const size_t res_bytes = (size_t)B_N * O_N * sizeof(float);  // 16 MB

  if (ws_size >= xT_bytes + idxT_bytes + res_bytes) {
    float* xT = (float*)d_ws;
    float* idxTf = (float*)((char*)d_ws + xT_bytes);
    float* res = (float*)((char*)d_ws + xT_bytes + idxT_bytes);

    const float* idxf = (const float*)idx;
    void* args[] = {(void*)&W,   (void*)&x,   (void*)&idxf, (void*)&bias,
                    (void*)&xT,  (void*)&idxTf, (void*)&res, (void*)&out};
    hipError_t e = hipLaunchCooperativeKernel(
        (const void*)fused_all, dim3(256), dim3(1024), args, 0, stream);
    if (e != hipSuccess) {
      // Fallback: proven R13 3-kernel pipeline.
      xpose_small<<<32, 256, 0, stream>>>(x, (const float*)idx, xT, idxTf);
      gemv_lds8<<<O_N / 16, 1024, 0, stream>>>(W, xT, (const int*)idxTf,
                                               bias, res);
      topk_phase<<<B_N, 256, 0, stream>>>(res, out);
    }
  } else {
    selgemv_topk<<<B_N, 256, 0, stream>>>(x, W, bias, idx, out);
  }
}

// Round 5
// 147.581 us; speedup vs baseline: 3.3701x; 3.3701x over previous
//
#include <hip/hip_runtime.h>
#include <stdint.h>

#define B_N 1024
#define K_N 64
#define O_N 4096
#define I_N 4096
#define H16S 260

typedef float nvec4 __attribute__((ext_vector_type(4)));

// ---------------------------------------------------------------------------
// Transpose x (B x K) -> xT (K x B) and idx likewise (bit-copy via float).
// ---------------------------------------------------------------------------
__global__ __launch_bounds__(256) void xpose_small(
    const float* __restrict__ x, const float* __restrict__ idxf,
    float* __restrict__ xT, float* __restrict__ idxTf) {
  __shared__ float tile[64][65];
  const int t = threadIdx.x;
  const int which = blockIdx.x >> 4;
  const int b0 = (blockIdx.x & 15) * 64;
  const float* src = which ? idxf : x;
  float* dst = which ? idxTf : xT;
  {
    const int r = t & 63;
    const int q0 = t >> 6;
#pragma unroll
    for (int jj = 0; jj < 4; ++jj) {
      const int q = q0 + 4 * jj;
      const float4 v = *(const float4*)(src + (size_t)(b0 + r) * K_N + 4 * q);
      tile[r][4 * q + 0] = v.x;
      tile[r][4 * q + 1] = v.y;
      tile[r][4 * q + 2] = v.z;
      tile[r][4 * q + 3] = v.w;
    }
  }
  __syncthreads();
  {
    const int kk = t & 63;
    const int q0 = t >> 6;
#pragma unroll
    for (int jj = 0; jj < 4; ++jj) {
      const int qb = q0 + 4 * jj;
      float4 v;
      v.x = tile[4 * qb + 0][kk];
      v.y = tile[4 * qb + 1][kk];
      v.z = tile[4 * qb + 2][kk];
      v.w = tile[4 * qb + 3][kk];
      *(float4*)(dst + (size_t)kk * B_N + b0 + 4 * qb) = v;
    }
  }
}

// ---------------------------------------------------------------------------
// gemv: EXACT R11/R13 WINNER (measured 45.0 us). 256 blocks, 2 passes x 8
// o-rows, 128 KB LDS, pass-1 tile prefetched to regs. Do not touch:
// - R12 deferred epilogue => scratch spill (FETCH +49MB, WRITE +80MB).
// - R14 cooperative fusion => grid.sync spins (11ms replays).
// - 2x res WRITE amplification is structural and L2-absorbed.
// Bit-exact: per (b,o) ascending-k chain, unfused mul/add, bias last.
// ---------------------------------------------------------------------------
#define GEMV_COMPUTE(G)                                                   \
  do {                                                                    \
    const int o0 = (G)*8;                                                 \
    const int b = t;                                                      \
    const float4 bvA = *(const float4*)(bias + o0);                       \
    const float4 bvB = *(const float4*)(bias + o0 + 4);                   \
    float4 aA = make_float4(0.f, 0.f, 0.f, 0.f);                          \
    float4 aB = make_float4(0.f, 0.f, 0.f, 0.f);                          \
    float xr[4];                                                          \
    int ir[4];                                                            \
    _Pragma("unroll") for (int d = 0; d < 4; ++d) {                       \
      xr[d] = xT[d * B_N + b];                                            \
      ir[d] = idxT[d * B_N + b];                                          \
    }                                                                     \
    _Pragma("unroll") for (int k = 0; k < K_N; ++k) {                     \
      const float xk = xr[k & 3];                                         \
      const int i = ir[k & 3];                                            \
      if (k + 4 < K_N) {                                                  \
        xr[k & 3] = xT[(k + 4) * B_N + b];                                \
        ir[k & 3] = idxT[(k + 4) * B_N + b];                              \
      }                                                                   \
      const float4 wA = Wi[i];                                            \
      const float4 wB = Wi[I_N + i];                                      \
      aA.x = __fadd_rn(aA.x, __fmul_rn(xk, wA.x));                        \
      aA.y = __fadd_rn(aA.y, __fmul_rn(xk, wA.y));                        \
      aA.z = __fadd_rn(aA.z, __fmul_rn(xk, wA.z));                        \
      aA.w = __fadd_rn(aA.w, __fmul_rn(xk, wA.w));                        \
      aB.x = __fadd_rn(aB.x, __fmul_rn(xk, wB.x));                        \
      aB.y = __fadd_rn(aB.y, __fmul_rn(xk, wB.y));                        \
      aB.z = __fadd_rn(aB.z, __fmul_rn(xk, wB.z));                        \
      aB.w = __fadd_rn(aB.w, __fmul_rn(xk, wB.w));                        \
    }                                                                     \
    aA.x = __fadd_rn(aA.x, bvA.x);                                        \
    aA.y = __fadd_rn(aA.y, bvA.y);                                        \
    aA.z = __fadd_rn(aA.z, bvA.z);                                        \
    aA.w = __fadd_rn(aA.w, bvA.w);                                        \
    aB.x = __fadd_rn(aB.x, bvB.x);                                        \
    aB.y = __fadd_rn(aB.y, bvB.y);                                        \
    aB.z = __fadd_rn(aB.z, bvB.z);                                        \
    aB.w = __fadd_rn(aB.w, bvB.w);                                        \
    *(float4*)(res + (size_t)b * O_N + o0) = aA;                          \
    *(float4*)(res + (size_t)b * O_N + o0 + 4) = aB;                      \
  } while (0)

__global__ __launch_bounds__(1024, 4) void gemv_lds8(
    const float* __restrict__ W, const float* __restrict__ xT,
    const int* __restrict__ idxT, const float* __restrict__ bias,
    float* __restrict__ res) {
  __shared__ float4 Wi[2 * I_N];  // 128 KB
  const int t = threadIdx.x;
  const int i0 = 4 * t;
  const int xcd = blockIdx.x & 7;
  const int jj = blockIdx.x >> 3;      // 0..31
  const int g0 = (xcd * 32 + jj) * 2;  // even 8-row group in [0,512)

  nvec4 r0, r1, r2, r3, r4, r5, r6, r7;
  {
    const float* Wp = W + (size_t)g0 * 8 * I_N + i0;
    r0 = __builtin_nontemporal_load((const nvec4*)(Wp + 0 * (size_t)I_N));
    r1 = __builtin_nontemporal_load((const nvec4*)(Wp + 1 * (size_t)I_N));
    r2 = __builtin_nontemporal_load((const nvec4*)(Wp + 2 * (size_t)I_N));
    r3 = __builtin_nontemporal_load((const nvec4*)(Wp + 3 * (size_t)I_N));
    r4 = __builtin_nontemporal_load((const nvec4*)(Wp + 4 * (size_t)I_N));
    r5 = __builtin_nontemporal_load((const nvec4*)(Wp + 5 * (size_t)I_N));
    r6 = __builtin_nontemporal_load((const nvec4*)(Wp + 6 * (size_t)I_N));
    r7 = __builtin_nontemporal_load((const nvec4*)(Wp + 7 * (size_t)I_N));
  }
  // stage pass 0
  Wi[i0 + 0] = make_float4(r0.x, r1.x, r2.x, r3.x);
  Wi[i0 + 1] = make_float4(r0.y, r1.y, r2.y, r3.y);
  Wi[i0 + 2] = make_float4(r0.z, r1.z, r2.z, r3.z);
  Wi[i0 + 3] = make_float4(r0.w, r1.w, r2.w, r3.w);
  Wi[I_N + i0 + 0] = make_float4(r4.x, r5.x, r6.x, r7.x);
  Wi[I_N + i0 + 1] = make_float4(r4.y, r5.y, r6.y, r7.y);
  Wi[I_N + i0 + 2] = make_float4(r4.z, r5.z, r6.z, r7.z);
  Wi[I_N + i0 + 3] = make_float4(r4.w, r5.w, r6.w, r7.w);
  // prefetch pass-1 tile into registers (latency hides under pass-0 k-loop)
  {
    const float* Wp = W + ((size_t)g0 + 1) * 8 * I_N + i0;
    r0 = __builtin_nontemporal_load((const nvec4*)(Wp + 0 * (size_t)I_N));
    r1 = __builtin_nontemporal_load((const nvec4*)(Wp + 1 * (size_t)I_N));
    r2 = __builtin_nontemporal_load((const nvec4*)(Wp + 2 * (size_t)I_N));
    r3 = __builtin_nontemporal_load((const nvec4*)(Wp + 3 * (size_t)I_N));
    r4 = __builtin_nontemporal_load((const nvec4*)(Wp + 4 * (size_t)I_N));
    r5 = __builtin_nontemporal_load((const nvec4*)(Wp + 5 * (size_t)I_N));
    r6 = __builtin_nontemporal_load((const nvec4*)(Wp + 6 * (size_t)I_N));
    r7 = __builtin_nontemporal_load((const nvec4*)(Wp + 7 * (size_t)I_N));
  }
  __syncthreads();

  GEMV_COMPUTE(g0);

  __syncthreads();  // all pass-0 reads done before overwriting the tile
  // stage pass 1 from prefetched registers
  Wi[i0 + 0] = make_float4(r0.x, r1.x, r2.x, r3.x);
  Wi[i0 + 1] = make_float4(r0.y, r1.y, r2.y, r3.y);
  Wi[i0 + 2] = make_float4(r0.z, r1.z, r2.z, r3.z);
  Wi[i0 + 3] = make_float4(r0.w, r1.w, r2.w, r3.w);
  Wi[I_N + i0 + 0] = make_float4(r4.x, r5.x, r6.x, r7.x);
  Wi[I_N + i0 + 1] = make_float4(r4.y, r5.y, r6.y, r7.y);
  Wi[I_N + i0 + 2] = make_float4(r4.z, r5.z, r6.z, r7.z);
  Wi[I_N + i0 + 3] = make_float4(r4.w, r5.w, r6.w, r7.w);
  __syncthreads();

  GEMV_COMPUTE(g0 + 1);
}

// ---------------------------------------------------------------------------
// R15 topk: 512 threads/block, 8 values/thread (was 256 thr x 16 vals).
// CU occupancy identical (4x512 = 8x256 = 2048 thr/CU; LDS 4x18.7KB < 160KB)
// but every per-thread serial chain halves: row load 2xfloat4, round-3
// 8 atomics, rounds 2-0 8 filtered checks, compaction 8. Scan/bitonic tail
// (t<64, wave 0) unchanged. 16-way salted round-3 histogram kept from R12.
// ---------------------------------------------------------------------------
__global__ __launch_bounds__(512) void topk_phase(
    const float* __restrict__ res, float* __restrict__ out) {
  __shared__ __align__(16) unsigned int hist[256];
  __shared__ __align__(16) unsigned int hist16[16 * H16S];
  __shared__ unsigned int sel_u[64];
  __shared__ int sel_i[64];
  __shared__ int eqlist[128];
  __shared__ unsigned int s_cntgt, s_cnteq;
  __shared__ unsigned int s_remaining, s_prefix;

  const int t = threadIdx.x;
  const int b = blockIdx.x;

  if (t < 256) hist[t] = 0u;
#pragma unroll
  for (int j = 0; j < 9; ++j) {
    const int z = t + 512 * j;
    if (z < 16 * H16S) hist16[z] = 0u;
  }
  if (t == 0) {
    s_remaining = 64u;
    s_prefix = 0u;
    s_cntgt = 0u;
    s_cnteq = 0u;
  }

  unsigned int myu[8];
#pragma unroll
  for (int jf = 0; jf < 2; ++jf) {
    const float4 v =
        *(const float4*)(res + (size_t)b * O_N + 2048 * jf + 4 * t);
    const float fv[4] = {v.x, v.y, v.z, v.w};
#pragma unroll
    for (int c = 0; c < 4; ++c) {
      const unsigned int s = __float_as_uint(fv[c]);
      myu[jf * 4 + c] = (s & 0x80000000u) ? ~s : (s | 0x80000000u);
    }
  }
  __syncthreads();

  for (int round = 3; round >= 0; --round) {
    const int shift = round * 8;
    const unsigned int pfx = s_prefix;
    const unsigned int rem = s_remaining;
    if (round == 3) {
      const int rep = (t & 15) * H16S;
#pragma unroll
      for (int j = 0; j < 8; ++j)
        atomicAdd(&hist16[rep + (myu[j] >> 24)], 1u);
    } else {
      const unsigned int himask = 0xFFFFFFFFu << (shift + 8);
#pragma unroll
      for (int j = 0; j < 8; ++j) {
        if ((myu[j] & himask) == (pfx & himask))
          atomicAdd(&hist[(myu[j] >> shift) & 255u], 1u);
      }
    }
    __syncthreads();
    if (t < 64) {
      uint4 h;
      if (round == 3) {
        h = make_uint4(0u, 0u, 0u, 0u);
#pragma unroll
        for (int r = 0; r < 16; ++r) {
          const uint4 hh = *(const uint4*)&hist16[r * H16S + 4 * t];
          h.x += hh.x;
          h.y += hh.y;
          h.z += hh.z;
          h.w += hh.w;
        }
      } else {
        h = *(const uint4*)&hist[4 * t];
      }
      unsigned int s0 = h.x + h.y + h.z + h.w;
      unsigned int run = s0;
#pragma unroll
      for (int off = 1; off < 64; off <<= 1) {
        const unsigned int v = __shfl_down(run, off, 64);
        if (t + off < 64) run += v;
      }
      const unsigned int above = run - s0;
      unsigned int cge[4], cgt[4];
      cgt[3] = above;
      cge[3] = above + h.w;
      cgt[2] = cge[3];
      cge[2] = cge[3] + h.z;
      cgt[1] = cge[2];
      cge[1] = cge[2] + h.y;
      cgt[0] = cge[1];
      cge[0] = cge[1] + h.x;
#pragma unroll
      for (int j = 0; j < 4; ++j) {
        if (cge[j] >= rem && cgt[j] < rem) {
          s_prefix = pfx | ((unsigned int)(4 * t + j) << shift);
          s_remaining = rem - cgt[j];
        }
      }
      *(uint4*)&hist[4 * t] = make_uint4(0u, 0u, 0u, 0u);
    }
    __syncthreads();
  }
  const unsigned int ustar = s_prefix;

#pragma unroll
  for (int j = 0; j < 8; ++j) {
    const unsigned int u = myu[j];
    const int oi = 4 * t + (j & 3) + 2048 * (j >> 2);
    if (u > ustar) {
      unsigned int p = atomicAdd(&s_cntgt, 1u);
      sel_u[p] = u;
      sel_i[p] = oi;
    } else if (u == ustar) {
      unsigned int p = atomicAdd(&s_cnteq, 1u);
      if (p < 128u) eqlist[p] = oi;
    }
  }
  __syncthreads();

  if (t == 0 && s_cnteq > 1u) {
    int n = (int)(s_cnteq < 128u ? s_cnteq : 128u);
    for (int a = 1; a < n; ++a) {
      int v = eqlist[a];
      int c = a;
      while (c > 0 && eqlist[c - 1] > v) {
        eqlist[c] = eqlist[c - 1];
        --c;
      }
      eqlist[c] = v;
    }
  }
  __syncthreads();

  if (t < 64) {
    const int n_gt = (int)s_cntgt;
    unsigned int u;
    int oi;
    if (t < n_gt) {
      u = sel_u[t];
      oi = sel_i[t];
    } else {
      u = ustar;
      oi = eqlist[t - n_gt];
    }
    unsigned long long key =
        ((unsigned long long)(~u) << 32) | (unsigned int)oi;
    for (int kk = 2; kk <= 64; kk <<= 1) {
      for (int jj = kk >> 1; jj > 0; jj >>= 1) {
        unsigned long long partner = __shfl_xor(key, jj, 64);
        const bool up = ((t & kk) == 0);
        const bool lower = ((t & jj) == 0);
        unsigned long long mn = key < partner ? key : partner;
        unsigned long long mx = key < partner ? partner : key;
        key = (up == lower) ? mn : mx;
      }
    }
    const unsigned int su = ~(unsigned int)(key >> 32);
    const int so = (int)(key & 0xFFFFFFFFu);
    const float f = (su & 0x80000000u) ? __uint_as_float(su ^ 0x80000000u)
                                       : __uint_as_float(~su);
    out[b * 64 + t] = f;
    out[B_N * 64 + b * 64 + t] = (float)so;
  }
}

// ---------------------------------------------------------------------------
// Fallback: fused single-kernel path on raw W (used only if ws is too small).
// ---------------------------------------------------------------------------
__global__ __launch_bounds__(256) void selgemv_topk(
    const float* __restrict__ x, const float* __restrict__ Wsrc,
    const float* __restrict__ bias, const int* __restrict__ idx,
    float* __restrict__ out) {
  __shared__ float sx[K_N];
  __shared__ int si[K_N];
  __shared__ float svals[O_N];
  __shared__ unsigned int hist[256];
  __shared__ unsigned int scan[256];
  __shared__ unsigned int sel_u[64];
  __shared__ int sel_i[64];
  __shared__ int eqlist[128];
  __shared__ unsigned int s_T, s_ngt, s_cntgt, s_cnteq;
  __shared__ unsigned int s_remaining, s_prefix;

  const int t = threadIdx.x;
  const int b = blockIdx.x;

  if (t < K_N) {
    sx[t] = x[b * K_N + t];
    si[t] = idx[b * K_N + t];
  }
  if (t == 0) {
    s_remaining = 64u;
    s_prefix = 0u;
    s_cntgt = 0u;
    s_cnteq = 0u;
  }
  __syncthreads();

  float acc[16];
#pragma unroll
  for (int j = 0; j < 16; ++j) acc[j] = 0.0f;

  for (int k = 0; k < K_N; ++k) {
    const float xk = sx[k];
    const int ik = si[k];
#pragma unroll
    for (int j = 0; j < 4; ++j) {
      int o0 = (j * 256 + t) * 4;
#pragma unroll
      for (int c = 0; c < 4; ++c) {
        float w = Wsrc[(size_t)(o0 + c) * I_N + ik];
        acc[4 * j + c] = __fadd_rn(acc[4 * j + c], __fmul_rn(xk, w));
      }
    }
  }

#pragma unroll
  for (int j = 0; j < 4; ++j) {
    int g = j * 256 + t;
    float4 bb = ((const float4*)bias)[g];
    float4 r;
    r.x = __fadd_rn(acc[4 * j + 0], bb.x);
    r.y = __fadd_rn(acc[4 * j + 1], bb.y);
    r.z = __fadd_rn(acc[4 * j + 2], bb.z);
    r.w = __fadd_rn(acc[4 * j + 3], bb.w);
    ((float4*)svals)[g] = r;
  }
  __syncthreads();

  unsigned int myu[16];
#pragma unroll
  for (int j = 0; j < 16; ++j) {
    float f = svals[t + 256 * j];
    unsigned int s = __float_as_uint(f);
    myu[j] = (s & 0x80000000u) ? ~s : (s | 0x80000000u);
  }

  for (int round = 3; round >= 0; --round) {
    const int shift = round * 8;
    hist[t] = 0u;
    __syncthreads();
    const unsigned int pfx = s_prefix;
    const unsigned int rem = s_remaining;
    const unsigned int himask =
        (round == 3) ? 0u : (0xFFFFFFFFu << (shift + 8));
#pragma unroll
    for (int j = 0; j < 16; ++j) {
      if ((myu[j] & himask) == (pfx & himask))
        atomicAdd(&hist[(myu[j] >> shift) & 255u], 1u);
    }
    __syncthreads();
    scan[t] = hist[t];
    __syncthreads();
    for (int off = 1; off < 256; off <<= 1) {
      unsigned int v = (t + off < 256) ? scan[t + off] : 0u;
      __syncthreads();
      scan[t] += v;
      __syncthreads();
    }
    const unsigned int c_ge = scan[t];
    const unsigned int c_gt = (t < 255) ? scan[t + 1] : 0u;
    if (c_ge >= rem && c_gt < rem) {
      s_T = (unsigned int)t;
      s_ngt = c_gt;
    }
    __syncthreads();
    if (t == 0) {
      s_prefix |= (s_T << shift);
      s_remaining -= s_ngt;
    }
    __syncthreads();
  }
  const unsigned int ustar = s_prefix;

#pragma unroll
  for (int j = 0; j < 16; ++j) {
    const unsigned int u = myu[j];
    if (u > ustar) {
      unsigned int p = atomicAdd(&s_cntgt, 1u);
      sel_u[p] = u;
      sel_i[p] = t + 256 * j;
    } else if (u == ustar) {
      unsigned int p = atomicAdd(&s_cnteq, 1u);
      if (p < 128u) eqlist[p] = t + 256 * j;
    }
  }
  __syncthreads();

  if (t == 0 && s_cnteq > 1u) {
    int n = (int)(s_cnteq < 128u ? s_cnteq : 128u);
    for (int a = 1; a < n; ++a) {
      int v = eqlist[a];
      int c = a;
      while (c > 0 && eqlist[c - 1] > v) {
        eqlist[c] = eqlist[c - 1];
        --c;
      }
      eqlist[c] = v;
    }
  }
  __syncthreads();

  if (t < 64) {
    const int n_gt = (int)s_cntgt;
    unsigned int u;
    int oi;
    if (t < n_gt) {
      u = sel_u[t];
      oi = sel_i[t];
    } else {
      u = ustar;
      oi = eqlist[t - n_gt];
    }
    unsigned long long key =
        ((unsigned long long)(~u) << 32) | (unsigned int)oi;
    for (int kk = 2; kk <= 64; kk <<= 1) {
      for (int jj = kk >> 1; jj > 0; jj >>= 1) {
        unsigned long long partner = __shfl_xor(key, jj, 64);
        const bool up = ((t & kk) == 0);
        const bool lower = ((t & jj) == 0);
        unsigned long long mn = key < partner ? key : partner;
        unsigned long long mx = key < partner ? partner : key;
        key = (up == lower) ? mn : mx;
      }
    }
    const unsigned int su = ~(unsigned int)(key >> 32);
    const int so = (int)(key & 0xFFFFFFFFu);
    const float f = (su & 0x80000000u) ? __uint_as_float(su ^ 0x80000000u)
                                       : __uint_as_float(~su);
    out[b * 64 + t] = f;
    out[B_N * 64 + b * 64 + t] = (float)so;
  }
}

extern "C" void kernel_launch(void* const* d_in, const int* in_sizes, int n_in,
                              void* d_out, int out_size, void* d_ws,
                              size_t ws_size, hipStream_t stream) {
  const float* x = (const float*)d_in[0];     // (1024, 64)
  const float* W = (const float*)d_in[1];     // (4096, 4096)
  const float* bias = (const float*)d_in[2];  // (4096,)
  const int* idx = (const int*)d_in[3];       // (1024, 64) int32
  float* out = (float*)d_out;

  const size_t xT_bytes = (size_t)K_N * B_N * sizeof(float);   // 256 KB
  const size_t idxT_bytes = xT_bytes;                          // 256 KB
  const size_t res_bytes = (size_t)B_N * O_N * sizeof(float);  // 16 MB

  if (ws_size >= xT_bytes + idxT_bytes + res_bytes) {
    float* xT = (float*)d_ws;
    float* idxTf = (float*)((char*)d_ws + xT_bytes);
    float* res = (float*)((char*)d_ws + xT_bytes + idxT_bytes);
    xpose_small<<<32, 256, 0, stream>>>(x, (const float*)idx, xT, idxTf);
    gemv_lds8<<<O_N / 16, 1024, 0, stream>>>(W, xT, (const int*)idxTf, bias,
                                             res);
    topk_phase<<<B_N, 512, 0, stream>>>(res, out);
  } else {
    selgemv_topk<<<B_N, 256, 0, stream>>>(x, W, bias, idx, out);
  }
}